// Round 11
// baseline (615.314 us; speedup 1.0000x reference)
//
#include <hip/hip_runtime.h>
#include <hip/hip_bf16.h>

typedef __attribute__((ext_vector_type(8))) short bf16x8;
typedef __attribute__((ext_vector_type(16))) float f32x16;
typedef __attribute__((ext_vector_type(4))) unsigned int u32x4;

#define KCAT 9216            // 1024 base cols + 1024*8 spline cols
#define NTOK 8192
#define CH   1024
#define KHALF 4608           // split-K half (per kz)
#define NT32 144             // K=32 tiles per block (4608/32)

// ---------- helpers ----------
__device__ __forceinline__ unsigned short f2bf(float f) {
    union { float f; unsigned int u; } v; v.f = f;
    unsigned int r = v.u + 0x7fffu + ((v.u >> 16) & 1u);   // RNE
    return (unsigned short)(r >> 16);
}

__device__ __forceinline__ void load16_to_lds(const void* gp, void* lp) {
    __builtin_amdgcn_global_load_lds(
        (__attribute__((address_space(1))) void*)(void*)gp,
        (__attribute__((address_space(3))) void*)lp,
        16, 0, 0);
}

// Closed-form uniform cubic B-spline (HW-validated round 5)
__device__ __forceinline__ void bases8_cf(float x, unsigned int* w) {
    float p  = (x + 0.44f) * 12.5f;
    float mf = floorf(p);
    float u  = p - mf;
    int   m  = (int)mf;
    float v  = 1.0f - u;
    float u2 = u * u, u3 = u2 * u;
    float N0 = v * v * v * (1.0f / 6.0f);
    float N1 = 0.5f * u3 - u2 + (2.0f / 3.0f);
    float N3 = u3 * (1.0f / 6.0f);
    float N2 = 1.0f - N0 - N1 - N3;
    unsigned long long lo =
          (unsigned long long)f2bf(N0)
        | ((unsigned long long)f2bf(N1) << 16)
        | ((unsigned long long)f2bf(N2) << 32)
        | ((unsigned long long)f2bf(N3) << 48);
    lo = (m >= 0 && m <= 10) ? lo : 0ull;
    int sh  = (m - 3) * 16;
    int sh1 = sh - 64;
    unsigned long long d0 =
        (sh  >= 0) ? ((sh  < 64) ? (lo << sh)    : 0ull)
                   : ((-sh  < 64) ? (lo >> (-sh))  : 0ull);
    unsigned long long d1 =
        (sh1 >= 0) ? ((sh1 < 64) ? (lo << sh1)   : 0ull)
                   : ((-sh1 < 64) ? (lo >> (-sh1)) : 0ull);
    w[0] = (unsigned int)d0; w[1] = (unsigned int)(d0 >> 32);
    w[2] = (unsigned int)d1; w[3] = (unsigned int)(d1 >> 32);
}

__device__ __forceinline__ void conv_w_body(const float* __restrict__ BW,
                                            const float* __restrict__ SW,
                                            unsigned short* __restrict__ W, int o) {
    const float* bw = BW + (size_t)o * 1024;
    const float* sw = SW + (size_t)o * 8192;
    unsigned short* w = W + (size_t)o * KCAT;
    for (int c = threadIdx.x * 4; c < KCAT; c += 256 * 4) {
        const float* src = (c < 1024) ? (bw + c) : (sw + (c - 1024));
        float4 v = *(const float4*)src;
        unsigned short u[4] = { f2bf(v.x), f2bf(v.y), f2bf(v.z), f2bf(v.w) };
        *(unsigned long long*)(w + c) = *(unsigned long long*)u;
    }
}

__device__ __forceinline__ void basis_body(float x, unsigned short* __restrict__ A, int idx) {
    int n = idx >> 10, i = idx & 1023;
    size_t rowbase = (size_t)n * KCAT;
    A[rowbase + i] = f2bf(x);
    unsigned int w[4];
    bases8_cf(x, w);
    *(u32x4*)(A + rowbase + 1024 + (size_t)i * 8) = (u32x4){w[0], w[1], w[2], w[3]};
}

// ---------- prep: blocks 0-1023 pack W1; 1024-3071 expand basis(x) ----------
__global__ __launch_bounds__(256) void prep1(const float* __restrict__ BW1,
                                             const float* __restrict__ SW1,
                                             unsigned short* __restrict__ W,
                                             const float* __restrict__ X,
                                             unsigned short* __restrict__ A) {
    int b = blockIdx.x;
    if (b < 1024) { conv_w_body(BW1, SW1, W, b); return; }
    int bb = b - 1024;
    for (int idx = bb * 256 + threadIdx.x; idx < NTOK * CH; idx += 2048 * 256)
        basis_body(X[idx], A, idx);
}

// ---------- mid: blocks 0-1023 pack W2; 1024-3071 expand basis(C0+C1) ----------
__global__ __launch_bounds__(256) void mid2(const float* __restrict__ BW2,
                                            const float* __restrict__ SW2,
                                            unsigned short* __restrict__ W,
                                            const float* __restrict__ C0,
                                            const float* __restrict__ C1,
                                            unsigned short* __restrict__ A) {
    int b = blockIdx.x;
    if (b < 1024) { conv_w_body(BW2, SW2, W, b); return; }
    int bb = b - 1024;
    for (int idx = bb * 256 + threadIdx.x; idx < NTOK * CH; idx += 2048 * 256)
        basis_body(C0[idx] + C1[idx], A, idx);
}

// ---------- final split-K reduction ----------
__global__ __launch_bounds__(256) void add_out(const float* __restrict__ C0,
                                               const float* __restrict__ C1,
                                               float* __restrict__ out, int total4) {
    for (int i = blockIdx.x * 256 + threadIdx.x; i < total4; i += gridDim.x * 256) {
        float4 a = ((const float4*)C0)[i];
        float4 b = ((const float4*)C1)[i];
        float4 r = { a.x + b.x, a.y + b.y, a.z + b.z, a.w + b.w };
        ((float4*)out)[i] = r;
    }
}

// ---------- 256x256 split-K GEMM: 32x32x16 MFMA + B-in-regs + A-ring ----------
// r4/r8/r9/r10 all ~150us @43-45%: tile time = DS + MFMA (sum). This cuts
// both terms: 32x32x16 (2x FLOP/instr, 2495 vs 2075 TF ceiling) and B loaded
// global->reg double-buffered with FULL-TILE prefetch distance (~2400cy cover;
// r7's 300cy cover was the failure). DS/tile: 128KB -> 80KB. A staging ring
// byte-identical to r9 (0 conflicts measured).
__global__ __launch_bounds__(512, 2) void gemm256_splitk(const unsigned short* __restrict__ A,
                                                         const unsigned short* __restrict__ B,
                                                         float* __restrict__ C0,
                                                         float* __restrict__ C1) {
    __shared__ __align__(16) unsigned short As[4 * 256 * 32];   // 64 KiB, 4 bufs
    const int tid  = threadIdx.x;
    const int lane = tid & 63;
    const int wid  = tid >> 6;
    const int wr = wid >> 2, wc = wid & 3;       // wave grid 2(M) x 4(N)
    const int l31 = lane & 31, h = lane >> 5;    // 32x32 fragment coords

    const int bid = blockIdx.x;                  // 0..255, XCD-partitioned
    const int xcd = bid & 7, ii = bid >> 3;
    const int kz = xcd & 1, chm = xcd >> 1;
    const int bm = chm * 8 + (ii & 7);           // 0..31
    const int bn = ii >> 3;                      // 0..3

    const unsigned short* Ab = A + (size_t)(bm * 256) * KCAT + (size_t)kz * KHALF;
    // per-lane B base: output-col row l31 within wave's 64-col strip
    const unsigned short* Bl = B + (size_t)(bn * 256 + wc * 64 + l31) * KCAT
                                 + (size_t)kz * KHALF + (size_t)h * 8;
    float* C = (kz == 0) ? C0 : C1;

    f32x16 acc[4][2] = {};
    bf16x8 b0[2][2], b1[2][2];                   // double-buffered B frags

    auto stageA = [&](int tile, int ds) {        // 2 vmem instrs/thread, 16KB
#pragma unroll
        for (int part = 0; part < 2; ++part) {
            int c = part * 512 + tid;            // 0..1023
            int r = c >> 2;                      // row 0..255
            int gslot = (c & 3) ^ ((r >> 1) & 3);
            size_t goff = (size_t)r * (KCAT * 2) + (size_t)tile * 64 + gslot * 16;
            load16_to_lds((const char*)Ab + goff, (char*)As + (size_t)ds * 16384 + c * 16);
        }
    };
    auto loadB = [&](bf16x8 (&dst)[2][2], int tile) {   // 4 x 16B gather
#pragma unroll
        for (int nf = 0; nf < 2; ++nf)
#pragma unroll
            for (int ks = 0; ks < 2; ++ks)
                dst[nf][ks] = *(const bf16x8*)(Bl + (size_t)nf * 32 * KCAT
                                                  + (size_t)tile * 32 + ks * 16);
    };
    auto compute = [&](const bf16x8 (&bfr)[2][2], int u) {
        const char* Ah = (const char*)As + u * 16384;
        bf16x8 afr[8];                           // [mf*2+ks]
#pragma unroll
        for (int mf = 0; mf < 4; ++mf)
#pragma unroll
            for (int ks = 0; ks < 2; ++ks) {
                int row = wr * 128 + mf * 32 + l31;
                int kslot = ks * 2 + h;
                afr[mf * 2 + ks] = *(const bf16x8*)(Ah + row * 64
                                      + ((kslot ^ ((row >> 1) & 3)) * 16));
            }
        __builtin_amdgcn_s_setprio(1);
#pragma unroll
        for (int ks = 0; ks < 2; ++ks)
#pragma unroll
            for (int mf = 0; mf < 4; ++mf)
#pragma unroll
                for (int nf = 0; nf < 2; ++nf)
                    acc[mf][nf] = __builtin_amdgcn_mfma_f32_32x32x16_bf16(
                        afr[mf * 2 + ks], bfr[nf][ks], acc[mf][nf], 0, 0, 0);
        __builtin_amdgcn_s_setprio(0);
    };

    // prologue: B(0)->b0, A(0)->buf0, A(1)->buf1; wait A(0) (A(1) in flight)
    loadB(b0, 0);
    stageA(0, 0);
    stageA(1, 1);
    asm volatile("s_waitcnt vmcnt(2)" ::: "memory");
    __builtin_amdgcn_s_barrier();

    // steady state, tiles 0..139 (both prefetches always valid: t+2 <= 141)
    for (int g = 0; g < 35; ++g) {
        const int t = g * 4;
#pragma unroll
        for (int u = 0; u < 4; ++u) {
            // FIFO at tile end: [A(t+1) x2 | B(t+1) x4 | A(t+2) x2] -> vmcnt(6)
            if ((u & 1) == 0) { loadB(b1, t + u + 1); stageA(t + u + 2, (u + 2) & 3); compute(b0, u); }
            else              { loadB(b0, t + u + 1); stageA(t + u + 2, (u + 2) & 3); compute(b1, u); }
            asm volatile("s_waitcnt vmcnt(6)" ::: "memory");
            __builtin_amdgcn_s_barrier();
        }
    }
    // tail: tiles 140..143 (bufs 0..3)
    { loadB(b1, 141); stageA(142, 2); compute(b0, 0);
      asm volatile("s_waitcnt vmcnt(6)" ::: "memory"); __builtin_amdgcn_s_barrier(); }
    { loadB(b0, 142); stageA(143, 3); compute(b1, 1);
      asm volatile("s_waitcnt vmcnt(6)" ::: "memory"); __builtin_amdgcn_s_barrier(); }
    { loadB(b1, 143); compute(b0, 2);
      asm volatile("s_waitcnt vmcnt(4)" ::: "memory"); __builtin_amdgcn_s_barrier(); }
    { compute(b1, 3); }

    // epilogue: 32x32 C/D layout col=lane&31, row=(reg&3)+8*(reg>>2)+4*(lane>>5)
    // [m74/m101-verified]
#pragma unroll
    for (int mf = 0; mf < 4; ++mf)
#pragma unroll
        for (int nf = 0; nf < 2; ++nf)
#pragma unroll
            for (int r = 0; r < 16; ++r) {
                int row = bm * 256 + wr * 128 + mf * 32 + (r & 3) + 8 * (r >> 2) + 4 * h;
                int col = bn * 256 + wc * 64 + nf * 32 + l31;
                C[(size_t)row * CH + col] = acc[mf][nf][r];
            }
}

// ---------- launch ----------
extern "C" void kernel_launch(void* const* d_in, const int* in_sizes, int n_in,
                              void* d_out, int out_size, void* d_ws, size_t ws_size,
                              hipStream_t stream) {
    const float* x   = (const float*)d_in[0];
    const float* bw1 = (const float*)d_in[1];
    const float* sw1 = (const float*)d_in[2];
    const float* bw2 = (const float*)d_in[3];
    const float* sw2 = (const float*)d_in[4];
    float* out = (float*)d_out;

    char* ws = (char*)d_ws;
    unsigned short* Abuf = (unsigned short*)ws;                    // 150,994,944 B
    unsigned short* Wbuf = (unsigned short*)(ws + 150994944);      //  18,874,368 B
    float* C0 = (float*)(ws + 150994944 + 18874368);               //  33,554,432 B
    float* C1 = (float*)(ws + 150994944 + 18874368 + 33554432);    //  33,554,432 B

    // layer 1
    prep1         <<<dim3(3072), dim3(256), 0, stream>>>(bw1, sw1, Wbuf, x, Abuf);
    gemm256_splitk<<<dim3(256), dim3(512), 0, stream>>>(Abuf, Wbuf, C0, C1);

    // layer 2 (W2 pack + split-K reduce + basis, one kernel)
    mid2          <<<dim3(3072), dim3(256), 0, stream>>>(bw2, sw2, Wbuf, C0, C1, Abuf);
    gemm256_splitk<<<dim3(256), dim3(512), 0, stream>>>(Abuf, Wbuf, C0, C1);
    add_out       <<<dim3(1024), dim3(256), 0, stream>>>(C0, C1, out, NTOK * CH / 4);
}